// Round 3
// baseline (460.998 us; speedup 1.0000x reference)
//
#include <hip/hip_runtime.h>
#include <cstdint>

#define CDIM 40
#define FDIM 128
#define WROW 44        // padded LDS row for W^T (16B-multiple, conflict-light)
#define SCAN_T 256
#define SCAN_E 1024

static __device__ __forceinline__ long long load_idx(const void* p, int is64, long long i) {
    if (is64) return ((const long long*)p)[i];
    return (long long)((const int*)p)[i];
}

static __device__ __forceinline__ void fma4(float4& a, float s, const float4& w) {
    a.x += s * w.x; a.y += s * w.y; a.z += s * w.z; a.w += s * w.w;
}
static __device__ __forceinline__ void add4(float4& a, const float4& v) {
    a.x += v.x; a.y += v.y; a.z += v.z; a.w += v.w;
}

// int64-vs-int32 detection (parallel): int64 little-endian values < 2^31 have
// all odd 32-bit words zero; impossible for ~1024 genuine int32 node ids.
__global__ void k_detect(const unsigned int* w, int nscan, int* flag) {
    __shared__ int bad;
    if (threadIdx.x == 0) bad = 0;
    __syncthreads();
    for (int k = 1 + 2 * (int)threadIdx.x; k < nscan; k += 2 * blockDim.x)
        if (w[k] != 0u) bad = 1;
    __syncthreads();
    if (threadIdx.x == 0) *flag = bad ? 0 : 1;
}

__global__ void k_zero(int* p, int n) {
    int i = blockIdx.x * blockDim.x + threadIdx.x;
    if (i < n) p[i] = 0;
}

__global__ void k_hist(const void* ei, const int* flag, long long E, int* cnt) {
    long long e = (long long)blockIdx.x * blockDim.x + threadIdx.x;
    if (e >= E) return;
    int is64 = *flag;
    long long d = load_idx(ei, is64, E + e);
    atomicAdd(&cnt[d], 1);
}

__global__ void k_scan1(const int* __restrict__ cnt, int N, int* __restrict__ row_ptr,
                        int* __restrict__ bsum) {
    __shared__ int ls[SCAN_T];
    int tid = threadIdx.x;
    int base = blockIdx.x * SCAN_E;
    int v[4], loc = 0;
#pragma unroll
    for (int k = 0; k < 4; ++k) {
        int idx = base + tid * 4 + k;
        v[k] = (idx < N) ? cnt[idx] : 0;
        loc += v[k];
    }
    ls[tid] = loc;
    __syncthreads();
    for (int off = 1; off < SCAN_T; off <<= 1) {
        int t = (tid >= off) ? ls[tid - off] : 0;
        __syncthreads();
        ls[tid] += t;
        __syncthreads();
    }
    int excl = ls[tid] - loc;
    if (tid == SCAN_T - 1) bsum[blockIdx.x] = ls[SCAN_T - 1];
    int run = excl;
#pragma unroll
    for (int k = 0; k < 4; ++k) {
        int idx = base + tid * 4 + k;
        if (idx < N) row_ptr[idx] = run;
        run += v[k];
    }
}

__global__ void k_scan2(int* bsum, int nb) {
    __shared__ int ls[SCAN_T];
    int tid = threadIdx.x;
    int v[4], loc = 0;
#pragma unroll
    for (int k = 0; k < 4; ++k) {
        int idx = tid * 4 + k;
        v[k] = (idx < nb) ? bsum[idx] : 0;
        loc += v[k];
    }
    ls[tid] = loc;
    __syncthreads();
    for (int off = 1; off < SCAN_T; off <<= 1) {
        int t = (tid >= off) ? ls[tid - off] : 0;
        __syncthreads();
        ls[tid] += t;
        __syncthreads();
    }
    int excl = ls[tid] - loc;
    int run = excl;
#pragma unroll
    for (int k = 0; k < 4; ++k) {
        int idx = tid * 4 + k;
        if (idx < nb) bsum[idx] = run;
        run += v[k];
    }
}

__global__ void k_scan3(int* __restrict__ row_ptr, const int* __restrict__ bsum,
                        int* __restrict__ cursor, const int* __restrict__ cnt,
                        float* __restrict__ dinv, int N) {
    int i = blockIdx.x * blockDim.x + threadIdx.x;
    if (i >= N) return;
    int rp = row_ptr[i] + bsum[i >> 10];
    row_ptr[i] = rp;
    cursor[i] = rp;
    dinv[i] = rsqrtf(1.0f + (float)cnt[i]);
}

// CSR holds src only (4B/edge); norms folded into dinv-scaling of h (g-space).
__global__ void k_reorder(const void* ei, const int* flag, long long E,
                          int* __restrict__ cursor, int* __restrict__ csr) {
    long long e = (long long)blockIdx.x * blockDim.x + threadIdx.x;
    if (e >= E) return;
    int is64 = *flag;
    int s = (int)load_idx(ei, is64, e);
    int d = (int)load_idx(ei, is64, E + e);
    int pos = atomicAdd(&cursor[d], 1);
    csr[pos] = s;
}

// g[i,c] = dinv[i] * sum_f x[i,f]*W[c,f].
// Block 320 = 32 node-groups x 10 channel-groups; thread: 4 nodes x 4 channels.
__global__ __launch_bounds__(320) void k_gemm(const float* __restrict__ x,
                                              const float* __restrict__ W,
                                              const float* __restrict__ dinv,
                                              float* __restrict__ g, int N) {
    __shared__ float wt[FDIM * WROW];  // [f][c], padded rows
    int tid = threadIdx.x;
    for (int idx = tid; idx < CDIM * FDIM; idx += 320) {
        int c = idx >> 7, f = idx & 127;
        wt[f * WROW + c] = W[idx];
    }
    __syncthreads();
    int tc = tid % 10;           // channel group (4 channels)
    int tn = tid / 10;           // node group (4 nodes)
    int n0 = blockIdx.x * 128 + tn * 4;
    if (n0 >= N) return;
    const float4* xr0 = (const float4*)(x + (size_t)(n0 + 0) * FDIM);
    const float4* xr1 = (const float4*)(x + (size_t)(n0 + 1) * FDIM);
    const float4* xr2 = (const float4*)(x + (size_t)(n0 + 2) * FDIM);
    const float4* xr3 = (const float4*)(x + (size_t)(n0 + 3) * FDIM);
    float4 acc0 = {0,0,0,0}, acc1 = {0,0,0,0}, acc2 = {0,0,0,0}, acc3 = {0,0,0,0};
#pragma unroll 4
    for (int f4 = 0; f4 < FDIM / 4; ++f4) {
        float4 x0 = xr0[f4], x1 = xr1[f4], x2 = xr2[f4], x3 = xr3[f4];
#pragma unroll
        for (int k = 0; k < 4; ++k) {
            int f = 4 * f4 + k;
            float4 wv = *(const float4*)&wt[f * WROW + tc * 4];
            float s0 = k == 0 ? x0.x : k == 1 ? x0.y : k == 2 ? x0.z : x0.w;
            float s1 = k == 0 ? x1.x : k == 1 ? x1.y : k == 2 ? x1.z : x1.w;
            float s2 = k == 0 ? x2.x : k == 1 ? x2.y : k == 2 ? x2.z : x2.w;
            float s3 = k == 0 ? x3.x : k == 1 ? x3.y : k == 2 ? x3.z : x3.w;
            fma4(acc0, s0, wv);
            fma4(acc1, s1, wv);
            fma4(acc2, s2, wv);
            fma4(acc3, s3, wv);
        }
    }
    float d0 = dinv[n0], d1 = dinv[n0 + 1], d2 = dinv[n0 + 2], d3 = dinv[n0 + 3];
    acc0.x *= d0; acc0.y *= d0; acc0.z *= d0; acc0.w *= d0;
    acc1.x *= d1; acc1.y *= d1; acc1.z *= d1; acc1.w *= d1;
    acc2.x *= d2; acc2.y *= d2; acc2.z *= d2; acc2.w *= d2;
    acc3.x *= d3; acc3.y *= d3; acc3.z *= d3; acc3.w *= d3;
    *(float4*)&g[(size_t)(n0 + 0) * CDIM + tc * 4] = acc0;
    *(float4*)&g[(size_t)(n0 + 1) * CDIM + tc * 4] = acc1;
    *(float4*)&g[(size_t)(n0 + 2) * CDIM + tc * 4] = acc2;
    *(float4*)&g[(size_t)(n0 + 3) * CDIM + tc * 4] = acc3;
}

// One hop in g-space: gout[i] = scale_i*(gin[i] + sum_{s in in(i)} gin[s]) (+b)
// scale = dinv^2 (mode 0) or dinv (mode 1, + bias). Thread per (node, 20-ch half).
__global__ void k_gather(const int* __restrict__ row_ptr, const int* __restrict__ cnt,
                         const int* __restrict__ csr, const float* __restrict__ dinv,
                         const float* __restrict__ gin, const float* __restrict__ b,
                         float* __restrict__ gout, int N, int mode) {
    unsigned t = blockIdx.x * blockDim.x + threadIdx.x;
    unsigned node = t >> 1, half = t & 1;
    if (node >= (unsigned)N) return;
    const float4* base = (const float4*)gin + half * 5;
    const float4* self = base + (size_t)node * 10;
    float4 a0 = self[0], a1 = self[1], a2 = self[2], a3 = self[3], a4 = self[4];
    int beg = row_ptr[node];
    int end = beg + cnt[node];
    for (int j = beg; j < end; ++j) {
        int s = csr[j];
        const float4* p = base + (size_t)s * 10;
        float4 v0 = p[0], v1 = p[1], v2 = p[2], v3 = p[3], v4 = p[4];
        add4(a0, v0); add4(a1, v1); add4(a2, v2); add4(a3, v3); add4(a4, v4);
    }
    float d = dinv[node];
    float scale = mode ? d : d * d;
    a0.x *= scale; a0.y *= scale; a0.z *= scale; a0.w *= scale;
    a1.x *= scale; a1.y *= scale; a1.z *= scale; a1.w *= scale;
    a2.x *= scale; a2.y *= scale; a2.z *= scale; a2.w *= scale;
    a3.x *= scale; a3.y *= scale; a3.z *= scale; a3.w *= scale;
    a4.x *= scale; a4.y *= scale; a4.z *= scale; a4.w *= scale;
    if (mode) {
        const float4* b4 = (const float4*)b + half * 5;
        add4(a0, b4[0]); add4(a1, b4[1]); add4(a2, b4[2]); add4(a3, b4[3]); add4(a4, b4[4]);
    }
    float4* o = (float4*)gout + (size_t)node * 10 + half * 5;
    o[0] = a0; o[1] = a1; o[2] = a2; o[3] = a3; o[4] = a4;
}

static inline size_t align256(size_t v) { return (v + 255) & ~(size_t)255; }

extern "C" void kernel_launch(void* const* d_in, const int* in_sizes, int n_in,
                              void* d_out, int out_size, void* d_ws, size_t ws_size,
                              hipStream_t stream) {
    const float* x  = (const float*)d_in[0];
    const void*  ei = d_in[1];
    const float* W  = (const float*)d_in[2];
    const float* b  = (const float*)d_in[3];
    float* out = (float*)d_out;

    const int N = in_sizes[0] / FDIM;                 // 100000
    const long long E = (long long)in_sizes[1] / 2;   // 1600000

    char* wsb = (char*)d_ws;
    size_t off = 0;
    int*   flag   = (int*)(wsb + off);   off = align256(off + 4);
    int*   cnt    = (int*)(wsb + off);   off = align256(off + (size_t)N * 4);
    int*   rowp   = (int*)(wsb + off);   off = align256(off + (size_t)N * 4);
    int*   cursor = (int*)(wsb + off);   off = align256(off + (size_t)N * 4);
    int*   bsum   = (int*)(wsb + off);   off = align256(off + 1024 * 4);
    float* dinv   = (float*)(wsb + off); off = align256(off + (size_t)N * 4);
    float* g0     = (float*)(wsb + off); off = align256(off + (size_t)N * CDIM * 4);
    float* g1     = (float*)(wsb + off); off = align256(off + (size_t)N * CDIM * 4);
    int*   csr    = (int*)(wsb + off);   off = align256(off + (size_t)E * 4);

    const int B = 256;
    const int nbN  = (N + B - 1) / B;
    const int nbE  = (int)((E + B - 1) / B);
    const int nb1  = (N + SCAN_E - 1) / SCAN_E;
    const int nbGE = (N + 127) / 128;                 // gemm blocks (320 thr)
    const int nbGA = (2 * N + B - 1) / B;             // gather blocks

    int nscan = (int)((2 * E < 4096) ? (2 * E) : 4096);

    k_detect <<<1, 256, 0, stream>>>((const unsigned int*)ei, nscan, flag);
    k_zero   <<<nbN, B, 0, stream>>>(cnt, N);
    k_hist   <<<nbE, B, 0, stream>>>(ei, flag, E, cnt);
    k_scan1  <<<nb1, SCAN_T, 0, stream>>>(cnt, N, rowp, bsum);
    k_scan2  <<<1, SCAN_T, 0, stream>>>(bsum, nb1);
    k_scan3  <<<nbN, B, 0, stream>>>(rowp, bsum, cursor, cnt, dinv, N);
    k_reorder<<<nbE, B, 0, stream>>>(ei, flag, E, cursor, csr);
    k_gemm   <<<nbGE, 320, 0, stream>>>(x, W, dinv, g0, N);
    k_gather <<<nbGA, B, 0, stream>>>(rowp, cnt, csr, dinv, g0, b, g1,  N, 0);
    k_gather <<<nbGA, B, 0, stream>>>(rowp, cnt, csr, dinv, g1, b, out, N, 1);
}

// Round 4
// 316.322 us; speedup vs baseline: 1.4574x; 1.4574x over previous
//
#include <hip/hip_runtime.h>
#include <hip/hip_fp16.h>
#include <cstdint>

#define CDIM 40
#define FDIM 128
#define WROW 44          // padded LDS row for W^T
#define SCAN_T 256
#define SCAN_E 1024
#define BIN_SHIFT 9      // 512 nodes per bin
#define BIN_SZ (1 << BIN_SHIFT)
#define CHUNK 8192       // edges per binning chunk
#define STAGE_CAP 15744  // LDS-staged csr ints per bin (62KB + 2KB cursors < 64KB)

static __device__ __forceinline__ long long load_idx(const void* p, int is64, long long i) {
    if (is64) return ((const long long*)p)[i];
    return (long long)((const int*)p)[i];
}

static __device__ __forceinline__ void fma4(float4& a, float s, const float4& w) {
    a.x += s * w.x; a.y += s * w.y; a.z += s * w.z; a.w += s * w.w;
}

static __device__ __forceinline__ unsigned packh2(float a, float b) {
    __half2 h;
    h.x = __float2half(a);
    h.y = __float2half(b);
    return *(unsigned*)&h;
}

// add 8 fp16 values (one uint4) into acc[0..8)
static __device__ __forceinline__ void addv(float* acc, uint4 v) {
    const __half2* h = (const __half2*)&v;
#pragma unroll
    for (int k = 0; k < 4; ++k) {
        float2 f = __half22float2(h[k]);
        acc[2 * k]     += f.x;
        acc[2 * k + 1] += f.y;
    }
}

// int64-vs-int32 detection: int64 little-endian values < 2^31 have all odd
// 32-bit words zero; impossible for ~2048 genuine int32 node ids.
__global__ void k_detect(const unsigned int* w, int nscan, int* flag) {
    __shared__ int bad;
    if (threadIdx.x == 0) bad = 0;
    __syncthreads();
    for (int k = 1 + 2 * (int)threadIdx.x; k < nscan; k += 2 * blockDim.x)
        if (w[k] != 0u) bad = 1;
    __syncthreads();
    if (threadIdx.x == 0) *flag = bad ? 0 : 1;
}

__global__ void k_zero(int* p, int n) {
    int i = blockIdx.x * blockDim.x + threadIdx.x;
    if (i < n) p[i] = 0;
}

// Pass A1: per-(chunk,bin) histogram (LDS) + global per-node degree (atomics).
__global__ __launch_bounds__(256) void kA1(const void* ei, const int* flag, long long E,
                                           int nb, int* __restrict__ cnt,
                                           int* __restrict__ bcnt) {
    __shared__ int lc[BIN_SZ];  // >= nb
    int tid = threadIdx.x;
    for (int i = tid; i < nb; i += 256) lc[i] = 0;
    __syncthreads();
    long long base = (long long)blockIdx.x * CHUNK;
    int is64 = *flag;
    for (int k = tid; k < CHUNK; k += 256) {
        long long e = base + k;
        if (e >= E) break;
        int d = (int)load_idx(ei, is64, E + e);
        atomicAdd(&lc[d >> BIN_SHIFT], 1);
        atomicAdd(&cnt[d], 1);
    }
    __syncthreads();
    for (int i = tid; i < nb; i += 256) bcnt[(size_t)blockIdx.x * nb + i] = lc[i];
}

__global__ void k_scan1(const int* __restrict__ cnt, int N, int* __restrict__ row_ptr,
                        int* __restrict__ bsum) {
    __shared__ int ls[SCAN_T];
    int tid = threadIdx.x;
    int base = blockIdx.x * SCAN_E;
    int v[4], loc = 0;
#pragma unroll
    for (int k = 0; k < 4; ++k) {
        int idx = base + tid * 4 + k;
        v[k] = (idx < N) ? cnt[idx] : 0;
        loc += v[k];
    }
    ls[tid] = loc;
    __syncthreads();
    for (int off = 1; off < SCAN_T; off <<= 1) {
        int t = (tid >= off) ? ls[tid - off] : 0;
        __syncthreads();
        ls[tid] += t;
        __syncthreads();
    }
    int excl = ls[tid] - loc;
    if (tid == SCAN_T - 1) bsum[blockIdx.x] = ls[SCAN_T - 1];
    int run = excl;
#pragma unroll
    for (int k = 0; k < 4; ++k) {
        int idx = base + tid * 4 + k;
        if (idx < N) row_ptr[idx] = run;
        run += v[k];
    }
}

__global__ void k_scan2(int* bsum, int nb) {
    __shared__ int ls[SCAN_T];
    int tid = threadIdx.x;
    int v[4], loc = 0;
#pragma unroll
    for (int k = 0; k < 4; ++k) {
        int idx = tid * 4 + k;
        v[k] = (idx < nb) ? bsum[idx] : 0;
        loc += v[k];
    }
    ls[tid] = loc;
    __syncthreads();
    for (int off = 1; off < SCAN_T; off <<= 1) {
        int t = (tid >= off) ? ls[tid - off] : 0;
        __syncthreads();
        ls[tid] += t;
        __syncthreads();
    }
    int excl = ls[tid] - loc;
    int run = excl;
#pragma unroll
    for (int k = 0; k < 4; ++k) {
        int idx = tid * 4 + k;
        if (idx < nb) bsum[idx] = run;
        run += v[k];
    }
}

// Finalize rowp (N+1 entries), cursor=rowp (fallback path), dinv=rsqrt(1+deg).
__global__ void k_scan3(int* __restrict__ row_ptr, const int* __restrict__ bsum,
                        int* __restrict__ cursor, const int* __restrict__ cnt,
                        float* __restrict__ dinv, int N, int E) {
    int i = blockIdx.x * blockDim.x + threadIdx.x;
    if (i == 0) row_ptr[N] = E;
    if (i >= N) return;
    int rp = row_ptr[i] + bsum[i >> 10];
    row_ptr[i] = rp;
    cursor[i] = rp;
    dinv[i] = rsqrtf(1.0f + (float)cnt[i]);
}

// Pass A2: per-bin exclusive scan over chunk counts -> per-(chunk,bin) bases.
__global__ __launch_bounds__(128) void kA2(const int* __restrict__ bcnt,
                                           int* __restrict__ bbase,
                                           const int* __restrict__ rowp,
                                           int nchunk, int nb) {
    __shared__ int ls[128];
    int b = blockIdx.x, tid = threadIdx.x;
    int carry = rowp[b << BIN_SHIFT];
    for (int c0 = 0; c0 < nchunk; c0 += 128) {
        int c = c0 + tid;
        int v = (c < nchunk) ? bcnt[(size_t)c * nb + b] : 0;
        ls[tid] = v;
        __syncthreads();
        for (int off = 1; off < 128; off <<= 1) {
            int t = (tid >= off) ? ls[tid - off] : 0;
            __syncthreads();
            ls[tid] += t;
            __syncthreads();
        }
        if (c < nchunk) bbase[(size_t)c * nb + b] = carry + ls[tid] - v;
        carry += ls[127];
        __syncthreads();
    }
}

// Pass A3: scatter edges into bin-grouped array, 4B packed {dlocal:9 | src:17}.
// Valid for N <= 131072 (here N=100000).
__global__ __launch_bounds__(256) void kA3(const void* ei, const int* flag, long long E,
                                           int nb, const int* __restrict__ bbase,
                                           unsigned* __restrict__ binned) {
    __shared__ int lbase[BIN_SZ];
    __shared__ int lcnt[BIN_SZ];
    int tid = threadIdx.x;
    for (int i = tid; i < nb; i += 256) {
        lbase[i] = bbase[(size_t)blockIdx.x * nb + i];
        lcnt[i] = 0;
    }
    __syncthreads();
    long long base = (long long)blockIdx.x * CHUNK;
    int is64 = *flag;
    for (int k = tid; k < CHUNK; k += 256) {
        long long e = base + k;
        if (e >= E) break;
        int s = (int)load_idx(ei, is64, e);
        int d = (int)load_idx(ei, is64, E + e);
        int bin = d >> BIN_SHIFT;
        int loc = atomicAdd(&lcnt[bin], 1);
        unsigned val = (unsigned)s | ((unsigned)(d & (BIN_SZ - 1)) << 17);
        binned[lbase[bin] + loc] = val;
    }
}

// Pass B: one block per bin; build csr segment in LDS, coalesced copy-out.
__global__ __launch_bounds__(256) void kB(const unsigned* __restrict__ binned,
                                          const int* __restrict__ rowp,
                                          int* __restrict__ cursor,
                                          int* __restrict__ csr, int N) {
    __shared__ int lcur[BIN_SZ];
    __shared__ int stage[STAGE_CAP];
    int b = blockIdx.x;
    int node0 = b << BIN_SHIFT;
    int node1 = min(node0 + BIN_SZ, N);
    int nn = node1 - node0;
    int base = rowp[node0];
    int nedges = rowp[node1] - base;
    int tid = threadIdx.x;
    if (nedges <= STAGE_CAP) {
        for (int i = tid; i < nn; i += 256) lcur[i] = rowp[node0 + i] - base;
        __syncthreads();
        for (int t = tid; t < nedges; t += 256) {
            unsigned v = binned[base + t];
            int src = (int)(v & 0x1FFFFu);
            int dl  = (int)(v >> 17);
            int p = atomicAdd(&lcur[dl], 1);
            stage[p] = src;
        }
        __syncthreads();
        for (int t = tid; t < nedges; t += 256) csr[base + t] = stage[t];
    } else {
        // overflow fallback (never hit for random graphs): global cursors
        for (int t = tid; t < nedges; t += 256) {
            unsigned v = binned[base + t];
            int src = (int)(v & 0x1FFFFu);
            int d = node0 + (int)(v >> 17);
            int p = atomicAdd(&cursor[d], 1);
            csr[p] = src;
        }
    }
}

// g[i,c] = fp16( dinv[i] * sum_f x[i,f]*W[c,f] ).
// Block 320 = 32 node-groups x 10 channel-groups; thread: 4 nodes x 4 channels.
// Requires N % 4 == 0 (N=100000).
__global__ __launch_bounds__(320) void k_gemm(const float* __restrict__ x,
                                              const float* __restrict__ W,
                                              const float* __restrict__ dinv,
                                              unsigned* __restrict__ g, int N) {
    __shared__ float wt[FDIM * WROW];
    int tid = threadIdx.x;
    for (int idx = tid; idx < CDIM * FDIM; idx += 320) {
        int c = idx >> 7, f = idx & 127;
        wt[f * WROW + c] = W[idx];
    }
    __syncthreads();
    int tc = tid % 10;
    int tn = tid / 10;
    int n0 = blockIdx.x * 128 + tn * 4;
    if (n0 >= N) return;
    const float4* xr0 = (const float4*)(x + (size_t)(n0 + 0) * FDIM);
    const float4* xr1 = (const float4*)(x + (size_t)(n0 + 1) * FDIM);
    const float4* xr2 = (const float4*)(x + (size_t)(n0 + 2) * FDIM);
    const float4* xr3 = (const float4*)(x + (size_t)(n0 + 3) * FDIM);
    float4 acc0 = {0,0,0,0}, acc1 = {0,0,0,0}, acc2 = {0,0,0,0}, acc3 = {0,0,0,0};
#pragma unroll 4
    for (int f4 = 0; f4 < FDIM / 4; ++f4) {
        float4 x0 = xr0[f4], x1 = xr1[f4], x2 = xr2[f4], x3 = xr3[f4];
#pragma unroll
        for (int k = 0; k < 4; ++k) {
            int f = 4 * f4 + k;
            float4 wv = *(const float4*)&wt[f * WROW + tc * 4];
            float s0 = k == 0 ? x0.x : k == 1 ? x0.y : k == 2 ? x0.z : x0.w;
            float s1 = k == 0 ? x1.x : k == 1 ? x1.y : k == 2 ? x1.z : x1.w;
            float s2 = k == 0 ? x2.x : k == 1 ? x2.y : k == 2 ? x2.z : x2.w;
            float s3 = k == 0 ? x3.x : k == 1 ? x3.y : k == 2 ? x3.z : x3.w;
            fma4(acc0, s0, wv);
            fma4(acc1, s1, wv);
            fma4(acc2, s2, wv);
            fma4(acc3, s3, wv);
        }
    }
    float d0 = dinv[n0], d1 = dinv[n0 + 1], d2 = dinv[n0 + 2], d3 = dinv[n0 + 3];
    uint2 o0, o1, o2, o3;
    o0.x = packh2(acc0.x * d0, acc0.y * d0); o0.y = packh2(acc0.z * d0, acc0.w * d0);
    o1.x = packh2(acc1.x * d1, acc1.y * d1); o1.y = packh2(acc1.z * d1, acc1.w * d1);
    o2.x = packh2(acc2.x * d2, acc2.y * d2); o2.y = packh2(acc2.z * d2, acc2.w * d2);
    o3.x = packh2(acc3.x * d3, acc3.y * d3); o3.y = packh2(acc3.z * d3, acc3.w * d3);
    ((uint2*)g)[(size_t)(n0 + 0) * 10 + tc] = o0;
    ((uint2*)g)[(size_t)(n0 + 1) * 10 + tc] = o1;
    ((uint2*)g)[(size_t)(n0 + 2) * 10 + tc] = o2;
    ((uint2*)g)[(size_t)(n0 + 3) * 10 + tc] = o3;
}

// One hop in g-space (fp16 rows, fp32 accumulate). Thread per node, full 40-ch row.
// mode 0: gout = fp16( dinv^2 * (self + sum) )     [hop 1]
// mode 1: gout = fp32( dinv   * (self + sum) + b ) [hop 2, final output]
__global__ __launch_bounds__(256) void k_gather(const int* __restrict__ rowp,
                                                const int* __restrict__ csr,
                                                const float* __restrict__ dinv,
                                                const unsigned* __restrict__ gin,
                                                const float* __restrict__ b,
                                                void* __restrict__ gout, int N, int mode) {
    int node = blockIdx.x * 256 + threadIdx.x;
    if (node >= N) return;
    const uint4* g4 = (const uint4*)gin;
    float acc[40];
#pragma unroll
    for (int i = 0; i < 40; ++i) acc[i] = 0.0f;
    {
        const uint4* p = g4 + (size_t)node * 5;
        uint4 v0 = p[0], v1 = p[1], v2 = p[2], v3 = p[3], v4 = p[4];
        addv(acc + 0, v0); addv(acc + 8, v1); addv(acc + 16, v2);
        addv(acc + 24, v3); addv(acc + 32, v4);
    }
    int j = rowp[node], end = rowp[node + 1];
    for (; j + 1 < end; j += 2) {
        int s0 = csr[j], s1 = csr[j + 1];
        const uint4* p0 = g4 + (size_t)s0 * 5;
        const uint4* p1 = g4 + (size_t)s1 * 5;
        uint4 a0 = p0[0], a1 = p0[1], a2 = p0[2], a3 = p0[3], a4 = p0[4];
        uint4 c0 = p1[0], c1 = p1[1], c2 = p1[2], c3 = p1[3], c4 = p1[4];
        addv(acc + 0, a0); addv(acc + 8, a1); addv(acc + 16, a2);
        addv(acc + 24, a3); addv(acc + 32, a4);
        addv(acc + 0, c0); addv(acc + 8, c1); addv(acc + 16, c2);
        addv(acc + 24, c3); addv(acc + 32, c4);
    }
    if (j < end) {
        int s0 = csr[j];
        const uint4* p0 = g4 + (size_t)s0 * 5;
        uint4 a0 = p0[0], a1 = p0[1], a2 = p0[2], a3 = p0[3], a4 = p0[4];
        addv(acc + 0, a0); addv(acc + 8, a1); addv(acc + 16, a2);
        addv(acc + 24, a3); addv(acc + 32, a4);
    }
    float d = dinv[node];
    if (mode == 0) {
        float s = d * d;
        uint4 o[5];
#pragma unroll
        for (int q = 0; q < 5; ++q) {
            unsigned* w = (unsigned*)&o[q];
#pragma unroll
            for (int k = 0; k < 4; ++k)
                w[k] = packh2(acc[q * 8 + 2 * k] * s, acc[q * 8 + 2 * k + 1] * s);
        }
        uint4* op = (uint4*)gout + (size_t)node * 5;
#pragma unroll
        for (int q = 0; q < 5; ++q) op[q] = o[q];
    } else {
        const float4* b4 = (const float4*)b;
        float4* op = (float4*)gout + (size_t)node * 10;
#pragma unroll
        for (int q = 0; q < 10; ++q) {
            float4 bv = b4[q];
            float4 ov;
            ov.x = acc[q * 4 + 0] * d + bv.x;
            ov.y = acc[q * 4 + 1] * d + bv.y;
            ov.z = acc[q * 4 + 2] * d + bv.z;
            ov.w = acc[q * 4 + 3] * d + bv.w;
            op[q] = ov;
        }
    }
}

static inline size_t align256(size_t v) { return (v + 255) & ~(size_t)255; }

extern "C" void kernel_launch(void* const* d_in, const int* in_sizes, int n_in,
                              void* d_out, int out_size, void* d_ws, size_t ws_size,
                              hipStream_t stream) {
    const float* x  = (const float*)d_in[0];
    const void*  ei = d_in[1];
    const float* W  = (const float*)d_in[2];
    const float* b  = (const float*)d_in[3];
    float* out = (float*)d_out;

    const int N = in_sizes[0] / FDIM;                 // 100000
    const long long E = (long long)in_sizes[1] / 2;   // 1600000

    const int nb     = (N + BIN_SZ - 1) >> BIN_SHIFT;        // 196 bins
    const int nchunk = (int)((E + CHUNK - 1) / CHUNK);       // 196 chunks

    char* wsb = (char*)d_ws;
    size_t off = 0;
    int*      flag   = (int*)(wsb + off);      off = align256(off + 4);
    int*      cnt    = (int*)(wsb + off);      off = align256(off + (size_t)N * 4);
    int*      rowp   = (int*)(wsb + off);      off = align256(off + (size_t)(N + 1) * 4);
    int*      cursor = (int*)(wsb + off);      off = align256(off + (size_t)N * 4);
    int*      bsum   = (int*)(wsb + off);      off = align256(off + 1024 * 4);
    float*    dinv   = (float*)(wsb + off);    off = align256(off + (size_t)N * 4);
    int*      bcnt   = (int*)(wsb + off);      off = align256(off + (size_t)nchunk * nb * 4);
    int*      bbase  = (int*)(wsb + off);      off = align256(off + (size_t)nchunk * nb * 4);
    unsigned* g0     = (unsigned*)(wsb + off); off = align256(off + (size_t)N * CDIM * 2);
    unsigned* g1     = (unsigned*)(wsb + off); off = align256(off + (size_t)N * CDIM * 2);
    unsigned* binned = (unsigned*)(wsb + off); off = align256(off + (size_t)E * 4);
    int*      csr    = (int*)(wsb + off);      off = align256(off + (size_t)E * 4);

    const int B = 256;
    const int nbN  = (N + B - 1) / B;
    const int nb1  = (N + SCAN_E - 1) / SCAN_E;
    const int nbGE = (N + 127) / 128;
    const int nbGA = (N + B - 1) / B;

    int nscan = (int)((2 * E < 4096) ? (2 * E) : 4096);

    k_detect<<<1, 256, 0, stream>>>((const unsigned int*)ei, nscan, flag);
    k_zero  <<<nbN, B, 0, stream>>>(cnt, N);
    kA1     <<<nchunk, B, 0, stream>>>(ei, flag, E, nb, cnt, bcnt);
    k_scan1 <<<nb1, SCAN_T, 0, stream>>>(cnt, N, rowp, bsum);
    k_scan2 <<<1, SCAN_T, 0, stream>>>(bsum, nb1);
    k_scan3 <<<nbN, B, 0, stream>>>(rowp, bsum, cursor, cnt, dinv, N, (int)E);
    kA2     <<<nb, 128, 0, stream>>>(bcnt, bbase, rowp, nchunk, nb);
    kA3     <<<nchunk, B, 0, stream>>>(ei, flag, E, nb, bbase, binned);
    kB      <<<nb, B, 0, stream>>>(binned, rowp, cursor, csr, N);
    k_gemm  <<<nbGE, 320, 0, stream>>>(x, W, dinv, g0, N);
    k_gather<<<nbGA, B, 0, stream>>>(rowp, csr, dinv, g0, b, (void*)g1, N, 0);
    k_gather<<<nbGA, B, 0, stream>>>(rowp, csr, dinv, g1, b, (void*)out, N, 1);
}

// Round 5
// 273.234 us; speedup vs baseline: 1.6872x; 1.1577x over previous
//
#include <hip/hip_runtime.h>
#include <hip/hip_fp16.h>
#include <cstdint>

#define CDIM 40
#define FDIM 128
#define WROW 44          // padded LDS row for W^T
#define BIN_SHIFT 9      // 512 nodes per bin
#define BIN_SZ (1 << BIN_SHIFT)
#define CHUNK 4096       // edges per binning chunk
#define STAGE_CAP 12288  // LDS-staged csr ints per bin (48KB)

static __device__ __forceinline__ long long load_idx(const void* p, int is64, long long i) {
    if (is64) return ((const long long*)p)[i];
    return (long long)((const int*)p)[i];
}

static __device__ __forceinline__ void fma4(float4& a, float s, const float4& w) {
    a.x += s * w.x; a.y += s * w.y; a.z += s * w.z; a.w += s * w.w;
}

static __device__ __forceinline__ unsigned packh2(float a, float b) {
    __half2 h;
    h.x = __float2half(a);
    h.y = __float2half(b);
    return *(unsigned*)&h;
}

// add 8 fp16 values (one uint4) into acc[0..8)
static __device__ __forceinline__ void addv(float* acc, uint4 v) {
    const __half2* h = (const __half2*)&v;
#pragma unroll
    for (int k = 0; k < 4; ++k) {
        float2 f = __half22float2(h[k]);
        acc[2 * k]     += f.x;
        acc[2 * k + 1] += f.y;
    }
}

// int64-vs-int32 detection: int64 little-endian values < 2^31 have all odd
// 32-bit words zero; impossible for ~2048 genuine int32 node ids.
__global__ void k_detect(const unsigned int* w, int nscan, int* flag) {
    __shared__ int bad;
    if (threadIdx.x == 0) bad = 0;
    __syncthreads();
    for (int k = 1 + 2 * (int)threadIdx.x; k < nscan; k += 2 * blockDim.x)
        if (w[k] != 0u) bad = 1;
    __syncthreads();
    if (threadIdx.x == 0) *flag = bad ? 0 : 1;
}

// Pass A1: per-(chunk,bin) histogram in LDS only. No global atomics.
__global__ __launch_bounds__(256) void kA1(const void* ei, const int* flag, long long E,
                                           int nb, int* __restrict__ bcnt) {
    __shared__ int lc[256];  // nb <= 256
    int tid = threadIdx.x;
    for (int i = tid; i < nb; i += 256) lc[i] = 0;
    __syncthreads();
    long long base = (long long)blockIdx.x * CHUNK;
    int is64 = *flag;
    for (int k = tid; k < CHUNK; k += 256) {
        long long e = base + k;
        if (e >= E) break;
        int d = (int)load_idx(ei, is64, E + e);
        atomicAdd(&lc[d >> BIN_SHIFT], 1);
    }
    __syncthreads();
    for (int i = tid; i < nb; i += 256) bcnt[(size_t)blockIdx.x * nb + i] = lc[i];
}

// Pass A2: per-bin exclusive scan over chunk counts -> within-bin local bases
// plus per-bin totals.
__global__ __launch_bounds__(128) void kA2(const int* __restrict__ bcnt,
                                           int* __restrict__ bbase,
                                           int* __restrict__ btot,
                                           int nchunk, int nb) {
    __shared__ int ls[128];
    int b = blockIdx.x, tid = threadIdx.x;
    int carry = 0;
    for (int c0 = 0; c0 < nchunk; c0 += 128) {
        int c = c0 + tid;
        int v = (c < nchunk) ? bcnt[(size_t)c * nb + b] : 0;
        ls[tid] = v;
        __syncthreads();
        for (int off = 1; off < 128; off <<= 1) {
            int t = (tid >= off) ? ls[tid - off] : 0;
            __syncthreads();
            ls[tid] += t;
            __syncthreads();
        }
        if (c < nchunk) bbase[(size_t)c * nb + b] = carry + ls[tid] - v;
        carry += ls[127];
        __syncthreads();
    }
    if (tid == 0) btot[b] = carry;
}

// Exclusive scan of per-bin totals (nb <= 256) -> binStart[nb+1].
__global__ __launch_bounds__(256) void kScanB(const int* __restrict__ btot,
                                              int* __restrict__ binStart, int nb, int E) {
    __shared__ int ls[256];
    int tid = threadIdx.x;
    int v = (tid < nb) ? btot[tid] : 0;
    ls[tid] = v;
    __syncthreads();
    for (int off = 1; off < 256; off <<= 1) {
        int t = (tid >= off) ? ls[tid - off] : 0;
        __syncthreads();
        ls[tid] += t;
        __syncthreads();
    }
    if (tid < nb) binStart[tid] = ls[tid] - v;
    if (tid == 0) binStart[nb] = E;
}

// Pass A3: scatter edges into bin-grouped array, 4B packed {dlocal:9 | src:17}.
// Valid for N <= 131072 (here N=100000).
__global__ __launch_bounds__(256) void kA3(const void* ei, const int* flag, long long E,
                                           int nb, const int* __restrict__ bbase,
                                           const int* __restrict__ binStart,
                                           unsigned* __restrict__ binned) {
    __shared__ int lbase[256];
    __shared__ int lcnt[256];
    int tid = threadIdx.x;
    for (int i = tid; i < nb; i += 256) {
        lbase[i] = binStart[i] + bbase[(size_t)blockIdx.x * nb + i];
        lcnt[i] = 0;
    }
    __syncthreads();
    long long base = (long long)blockIdx.x * CHUNK;
    int is64 = *flag;
    for (int k = tid; k < CHUNK; k += 256) {
        long long e = base + k;
        if (e >= E) break;
        int s = (int)load_idx(ei, is64, e);
        int d = (int)load_idx(ei, is64, E + e);
        int bin = d >> BIN_SHIFT;
        int loc = atomicAdd(&lcnt[bin], 1);
        unsigned val = (unsigned)s | ((unsigned)(d & (BIN_SZ - 1)) << 17);
        binned[lbase[bin] + loc] = val;
    }
}

// Pass B: one block per bin. From binned records derive per-node degree
// (LDS histogram), rowp, dinv, a degree-sorted node permutation, and the
// CSR segment (built in LDS, coalesced copy-out).
__global__ __launch_bounds__(256) void kB(const unsigned* __restrict__ binned,
                                          const int* __restrict__ binStart,
                                          int* __restrict__ rowp, float* __restrict__ dinv,
                                          int* __restrict__ perm, int* __restrict__ cursorG,
                                          int* __restrict__ csr, int N, int E) {
    __shared__ int lcnt[BIN_SZ];
    __shared__ int lexcl[BIN_SZ];
    __shared__ int ls[256];
    __shared__ int dh[64];
    __shared__ int stage[STAGE_CAP];
    int b = blockIdx.x, tid = threadIdx.x;
    int node0 = b << BIN_SHIFT;
    int node1 = min(node0 + BIN_SZ, N);
    int nn = node1 - node0;
    int base = binStart[b];
    int nedges = binStart[b + 1] - base;

    for (int i = tid; i < BIN_SZ; i += 256) lcnt[i] = 0;
    if (tid < 64) dh[tid] = 0;
    __syncthreads();
    // per-node degree histogram
    for (int t = tid; t < nedges; t += 256)
        atomicAdd(&lcnt[binned[base + t] >> 17], 1);
    __syncthreads();
    // exclusive scan of 512 counts (thread owns elements 2t, 2t+1)
    int c0 = lcnt[2 * tid], c1 = lcnt[2 * tid + 1];
    int loc = c0 + c1;
    ls[tid] = loc;
    __syncthreads();
    for (int off = 1; off < 256; off <<= 1) {
        int t = (tid >= off) ? ls[tid - off] : 0;
        __syncthreads();
        ls[tid] += t;
        __syncthreads();
    }
    int ex = ls[tid] - loc;
    lexcl[2 * tid] = ex;
    lexcl[2 * tid + 1] = ex + c0;
    __syncthreads();
    // rowp, dinv, degree-bucket histogram
    for (int i = tid; i < nn; i += 256) {
        int deg = lcnt[i];
        rowp[node0 + i] = base + lexcl[i];
        dinv[node0 + i] = rsqrtf(1.0f + (float)deg);
        atomicAdd(&dh[min(deg, 63)], 1);
    }
    if (b == 0 && tid == 0) rowp[N] = E;
    __syncthreads();
    // exclusive scan of 64 degree buckets
    int dv = (tid < 64) ? dh[tid] : 0;
    ls[tid] = dv;
    __syncthreads();
    for (int off = 1; off < 64; off <<= 1) {
        int t = (tid >= off) ? ls[tid - off] : 0;
        __syncthreads();
        ls[tid] += t;
        __syncthreads();
    }
    if (tid < 64) dh[tid] = ls[tid] - dv;
    __syncthreads();
    // degree-sorted permutation (ascending degree within bin)
    for (int i = tid; i < nn; i += 256) {
        int pos = atomicAdd(&dh[min(lcnt[i], 63)], 1);
        perm[node0 + pos] = node0 + i;
    }
    // cursors = lexcl
    for (int i = tid; i < BIN_SZ; i += 256) {
        int v = lexcl[i];
        __syncthreads();  // ensure lcnt reads above done before overwrite
        lcnt[i] = v;
        break;  // (loop runs once; BIN_SZ==2*256 handled below)
    }
    __syncthreads();
    for (int i = tid; i < BIN_SZ; i += 256) lcnt[i] = lexcl[i];
    __syncthreads();
    if (nedges <= STAGE_CAP) {
        for (int t = tid; t < nedges; t += 256) {
            unsigned v = binned[base + t];
            int src = (int)(v & 0x1FFFFu);
            int dl  = (int)(v >> 17);
            int p = atomicAdd(&lcnt[dl], 1);
            stage[p] = src;
        }
        __syncthreads();
        for (int t = tid; t < nedges; t += 256) csr[base + t] = stage[t];
    } else {
        // overflow fallback: global cursors (rowp already holds bases)
        for (int i = tid; i < nn; i += 256) cursorG[node0 + i] = base + lexcl[i];
        __syncthreads();
        for (int t = tid; t < nedges; t += 256) {
            unsigned v = binned[base + t];
            int src = (int)(v & 0x1FFFFu);
            int dl  = (int)(v >> 17);
            int p = atomicAdd(&cursorG[node0 + dl], 1);
            csr[p] = src;
        }
    }
}

// g[i,c] = fp16( dinv[i] * sum_f x[i,f]*W[c,f] ).
// Block 320 = 32 node-groups x 10 channel-groups; thread: 4 nodes x 4 channels.
__global__ __launch_bounds__(320) void k_gemm(const float* __restrict__ x,
                                              const float* __restrict__ W,
                                              const float* __restrict__ dinv,
                                              unsigned* __restrict__ g, int N) {
    __shared__ float wt[FDIM * WROW];
    int tid = threadIdx.x;
    for (int idx = tid; idx < CDIM * FDIM; idx += 320) {
        int c = idx >> 7, f = idx & 127;
        wt[f * WROW + c] = W[idx];
    }
    __syncthreads();
    int tc = tid % 10;
    int tn = tid / 10;
    int n0 = blockIdx.x * 128 + tn * 4;
    if (n0 >= N) return;
    const float4* xr0 = (const float4*)(x + (size_t)(n0 + 0) * FDIM);
    const float4* xr1 = (const float4*)(x + (size_t)(n0 + 1) * FDIM);
    const float4* xr2 = (const float4*)(x + (size_t)(n0 + 2) * FDIM);
    const float4* xr3 = (const float4*)(x + (size_t)(n0 + 3) * FDIM);
    float4 acc0 = {0,0,0,0}, acc1 = {0,0,0,0}, acc2 = {0,0,0,0}, acc3 = {0,0,0,0};
#pragma unroll 4
    for (int f4 = 0; f4 < FDIM / 4; ++f4) {
        float4 x0 = xr0[f4], x1 = xr1[f4], x2 = xr2[f4], x3 = xr3[f4];
#pragma unroll
        for (int k = 0; k < 4; ++k) {
            int f = 4 * f4 + k;
            float4 wv = *(const float4*)&wt[f * WROW + tc * 4];
            float s0 = k == 0 ? x0.x : k == 1 ? x0.y : k == 2 ? x0.z : x0.w;
            float s1 = k == 0 ? x1.x : k == 1 ? x1.y : k == 2 ? x1.z : x1.w;
            float s2 = k == 0 ? x2.x : k == 1 ? x2.y : k == 2 ? x2.z : x2.w;
            float s3 = k == 0 ? x3.x : k == 1 ? x3.y : k == 2 ? x3.z : x3.w;
            fma4(acc0, s0, wv);
            fma4(acc1, s1, wv);
            fma4(acc2, s2, wv);
            fma4(acc3, s3, wv);
        }
    }
    float d0 = dinv[n0], d1 = dinv[n0 + 1], d2 = dinv[n0 + 2], d3 = dinv[n0 + 3];
    uint2 o0, o1, o2, o3;
    o0.x = packh2(acc0.x * d0, acc0.y * d0); o0.y = packh2(acc0.z * d0, acc0.w * d0);
    o1.x = packh2(acc1.x * d1, acc1.y * d1); o1.y = packh2(acc1.z * d1, acc1.w * d1);
    o2.x = packh2(acc2.x * d2, acc2.y * d2); o2.y = packh2(acc2.z * d2, acc2.w * d2);
    o3.x = packh2(acc3.x * d3, acc3.y * d3); o3.y = packh2(acc3.z * d3, acc3.w * d3);
    ((uint2*)g)[(size_t)(n0 + 0) * 10 + tc] = o0;
    ((uint2*)g)[(size_t)(n0 + 1) * 10 + tc] = o1;
    ((uint2*)g)[(size_t)(n0 + 2) * 10 + tc] = o2;
    ((uint2*)g)[(size_t)(n0 + 3) * 10 + tc] = o3;
}

// One hop in g-space (fp16 rows, fp32 accumulate). Thread per node via
// degree-sorted perm (uniform wave workloads). 2-edge unroll for MLP.
// mode 0: gout = fp16( dinv^2 * (self + sum) )     [hop 1]
// mode 1: gout = fp32( dinv   * (self + sum) + b ) [hop 2, final output]
__global__ __launch_bounds__(256) void k_gather(const int* __restrict__ rowp,
                                                const int* __restrict__ csr,
                                                const int* __restrict__ perm,
                                                const float* __restrict__ dinv,
                                                const unsigned* __restrict__ gin,
                                                const float* __restrict__ b,
                                                void* __restrict__ gout, int N, int mode) {
    int gid = blockIdx.x * 256 + threadIdx.x;
    if (gid >= N) return;
    int node = perm[gid];
    const uint4* g4 = (const uint4*)gin;
    float acc[40];
#pragma unroll
    for (int i = 0; i < 40; ++i) acc[i] = 0.0f;
    {
        const uint4* p = g4 + (size_t)node * 5;
        uint4 v0 = p[0], v1 = p[1], v2 = p[2], v3 = p[3], v4 = p[4];
        addv(acc + 0, v0); addv(acc + 8, v1); addv(acc + 16, v2);
        addv(acc + 24, v3); addv(acc + 32, v4);
    }
    int j = rowp[node], end = rowp[node + 1];
    for (; j + 1 < end; j += 2) {
        int s0 = csr[j], s1 = csr[j + 1];
        const uint4* p0 = g4 + (size_t)s0 * 5;
        const uint4* p1 = g4 + (size_t)s1 * 5;
        uint4 a0 = p0[0], a1 = p0[1], a2 = p0[2], a3 = p0[3], a4 = p0[4];
        uint4 c0 = p1[0], c1 = p1[1], c2 = p1[2], c3 = p1[3], c4 = p1[4];
        addv(acc + 0, a0); addv(acc + 8, a1); addv(acc + 16, a2);
        addv(acc + 24, a3); addv(acc + 32, a4);
        addv(acc + 0, c0); addv(acc + 8, c1); addv(acc + 16, c2);
        addv(acc + 24, c3); addv(acc + 32, c4);
    }
    if (j < end) {
        int s0 = csr[j];
        const uint4* p0 = g4 + (size_t)s0 * 5;
        uint4 a0 = p0[0], a1 = p0[1], a2 = p0[2], a3 = p0[3], a4 = p0[4];
        addv(acc + 0, a0); addv(acc + 8, a1); addv(acc + 16, a2);
        addv(acc + 24, a3); addv(acc + 32, a4);
    }
    float d = dinv[node];
    if (mode == 0) {
        float s = d * d;
        uint4 o[5];
#pragma unroll
        for (int q = 0; q < 5; ++q) {
            unsigned* w = (unsigned*)&o[q];
#pragma unroll
            for (int k = 0; k < 4; ++k)
                w[k] = packh2(acc[q * 8 + 2 * k] * s, acc[q * 8 + 2 * k + 1] * s);
        }
        uint4* op = (uint4*)gout + (size_t)node * 5;
#pragma unroll
        for (int q = 0; q < 5; ++q) op[q] = o[q];
    } else {
        const float4* b4 = (const float4*)b;
        float4* op = (float4*)gout + (size_t)node * 10;
#pragma unroll
        for (int q = 0; q < 10; ++q) {
            float4 bv = b4[q];
            float4 ov;
            ov.x = acc[q * 4 + 0] * d + bv.x;
            ov.y = acc[q * 4 + 1] * d + bv.y;
            ov.z = acc[q * 4 + 2] * d + bv.z;
            ov.w = acc[q * 4 + 3] * d + bv.w;
            op[q] = ov;
        }
    }
}

static inline size_t align256(size_t v) { return (v + 255) & ~(size_t)255; }

extern "C" void kernel_launch(void* const* d_in, const int* in_sizes, int n_in,
                              void* d_out, int out_size, void* d_ws, size_t ws_size,
                              hipStream_t stream) {
    const float* x  = (const float*)d_in[0];
    const void*  ei = d_in[1];
    const float* W  = (const float*)d_in[2];
    const float* b  = (const float*)d_in[3];
    float* out = (float*)d_out;

    const int N = in_sizes[0] / FDIM;                 // 100000
    const long long E = (long long)in_sizes[1] / 2;   // 1600000

    const int nb     = (N + BIN_SZ - 1) >> BIN_SHIFT;        // 196 bins
    const int nchunk = (int)((E + CHUNK - 1) / CHUNK);       // 391 chunks

    char* wsb = (char*)d_ws;
    size_t off = 0;
    int*      flag     = (int*)(wsb + off);      off = align256(off + 4);
    int*      bcnt     = (int*)(wsb + off);      off = align256(off + (size_t)nchunk * nb * 4);
    int*      bbase    = (int*)(wsb + off);      off = align256(off + (size_t)nchunk * nb * 4);
    int*      btot     = (int*)(wsb + off);      off = align256(off + (size_t)nb * 4);
    int*      binStart = (int*)(wsb + off);      off = align256(off + (size_t)(nb + 1) * 4);
    int*      rowp     = (int*)(wsb + off);      off = align256(off + (size_t)(N + 1) * 4);
    int*      cursorG  = (int*)(wsb + off);      off = align256(off + (size_t)N * 4);
    int*      perm     = (int*)(wsb + off);      off = align256(off + (size_t)N * 4);
    float*    dinv     = (float*)(wsb + off);    off = align256(off + (size_t)N * 4);
    unsigned* g0       = (unsigned*)(wsb + off); off = align256(off + (size_t)N * CDIM * 2);
    unsigned* g1       = (unsigned*)(wsb + off); off = align256(off + (size_t)N * CDIM * 2);
    unsigned* binned   = (unsigned*)(wsb + off); off = align256(off + (size_t)E * 4);
    int*      csr      = (int*)(wsb + off);      off = align256(off + (size_t)E * 4);

    const int B = 256;
    const int nbGE = (N + 127) / 128;
    const int nbGA = (N + B - 1) / B;

    int nscan = (int)((2 * E < 4096) ? (2 * E) : 4096);

    k_detect<<<1, 256, 0, stream>>>((const unsigned int*)ei, nscan, flag);
    kA1     <<<nchunk, B, 0, stream>>>(ei, flag, E, nb, bcnt);
    kA2     <<<nb, 128, 0, stream>>>(bcnt, bbase, btot, nchunk, nb);
    kScanB  <<<1, 256, 0, stream>>>(btot, binStart, nb, (int)E);
    kA3     <<<nchunk, B, 0, stream>>>(ei, flag, E, nb, bbase, binStart, binned);
    kB      <<<nb, B, 0, stream>>>(binned, binStart, rowp, dinv, perm, cursorG, csr, N, (int)E);
    k_gemm  <<<nbGE, 320, 0, stream>>>(x, W, dinv, g0, N);
    k_gather<<<nbGA, B, 0, stream>>>(rowp, csr, perm, dinv, g0, b, (void*)g1, N, 0);
    k_gather<<<nbGA, B, 0, stream>>>(rowp, csr, perm, dinv, g1, b, (void*)out, N, 1);
}

// Round 6
// 258.927 us; speedup vs baseline: 1.7804x; 1.0553x over previous
//
#include <hip/hip_runtime.h>
#include <hip/hip_fp16.h>
#include <cstdint>

#define CDIM 40
#define FDIM 128
#define WROW 44          // padded LDS row for W^T
#define BIN_SHIFT 9      // 512 nodes per bin
#define BIN_SZ (1 << BIN_SHIFT)
#define CHUNK 4096       // edges per binning chunk
#define STAGE_CAP 12288  // LDS-staged csr ints per bin (48KB)

static __device__ __forceinline__ long long load_idx(const void* p, int is64, long long i) {
    if (is64) return ((const long long*)p)[i];
    return (long long)((const int*)p)[i];
}

static __device__ __forceinline__ void fma4(float4& a, float s, const float4& w) {
    a.x += s * w.x; a.y += s * w.y; a.z += s * w.z; a.w += s * w.w;
}

static __device__ __forceinline__ unsigned packh2(float a, float b) {
    __half2 h;
    h.x = __float2half(a);
    h.y = __float2half(b);
    return *(unsigned*)&h;
}

// add 8 fp16 values (one uint4) into acc[0..8)
static __device__ __forceinline__ void addv(float* acc, uint4 v) {
    const __half2* h = (const __half2*)&v;
#pragma unroll
    for (int k = 0; k < 4; ++k) {
        float2 f = __half22float2(h[k]);
        acc[2 * k]     += f.x;
        acc[2 * k + 1] += f.y;
    }
}

// int64-vs-int32 detection + btot zeroing. int64 little-endian values < 2^31
// have all odd 32-bit words zero; impossible for ~2048 genuine int32 node ids.
__global__ void k_detect(const unsigned int* w, int nscan, int* flag,
                         int* btot, int nb) {
    __shared__ int bad;
    if (threadIdx.x == 0) bad = 0;
    __syncthreads();
    for (int k = 1 + 2 * (int)threadIdx.x; k < nscan; k += 2 * blockDim.x)
        if (w[k] != 0u) bad = 1;
    for (int i = threadIdx.x; i < nb; i += blockDim.x) btot[i] = 0;
    __syncthreads();
    if (threadIdx.x == 0) *flag = bad ? 0 : 1;
}

// Per-chunk LDS bin histogram -> one global atomicAdd per (block,bin).
__global__ __launch_bounds__(256) void kCount(const void* ei, const int* flag, long long E,
                                              int nb, int* __restrict__ btot) {
    __shared__ int lc[256];  // nb <= 256
    int tid = threadIdx.x;
    for (int i = tid; i < nb; i += 256) lc[i] = 0;
    __syncthreads();
    long long base = (long long)blockIdx.x * CHUNK;
    int is64 = *flag;
    for (int k = tid; k < CHUNK; k += 256) {
        long long e = base + k;
        if (e >= E) break;
        int d = (int)load_idx(ei, is64, E + e);
        atomicAdd(&lc[d >> BIN_SHIFT], 1);
    }
    __syncthreads();
    for (int i = tid; i < nb; i += 256) {
        int v = lc[i];
        if (v) atomicAdd(&btot[i], v);
    }
}

// Exclusive scan of per-bin totals (nb <= 256) -> binStart[nb+1], cursor init.
__global__ __launch_bounds__(256) void kScanB(const int* __restrict__ btot,
                                              int* __restrict__ binStart,
                                              int* __restrict__ cursor, int nb, int E) {
    __shared__ int ls[256];
    int tid = threadIdx.x;
    int v = (tid < nb) ? btot[tid] : 0;
    ls[tid] = v;
    __syncthreads();
    for (int off = 1; off < 256; off <<= 1) {
        int t = (tid >= off) ? ls[tid - off] : 0;
        __syncthreads();
        ls[tid] += t;
        __syncthreads();
    }
    if (tid < nb) {
        int s = ls[tid] - v;
        binStart[tid] = s;
        cursor[tid] = s;
    }
    if (tid == 0) binStart[nb] = E;
}

// Binning scatter: stage chunk edges in LDS (single global read of src+dst),
// reserve per-bin ranges via global cursors, scatter 4B packed
// {dlocal:9 | src:17}. Valid for N <= 131072.
__global__ __launch_bounds__(256) void kA3(const void* ei, const int* flag, long long E,
                                           int nb, int* __restrict__ cursor,
                                           unsigned* __restrict__ binned) {
    __shared__ unsigned lval[CHUNK];
    __shared__ unsigned char lbin[CHUNK];
    __shared__ int lcnt[256];
    __shared__ int lbase[256];
    int tid = threadIdx.x;
    for (int i = tid; i < nb; i += 256) lcnt[i] = 0;
    __syncthreads();
    long long base = (long long)blockIdx.x * CHUNK;
    int nk = (int)min((long long)CHUNK, E - base);
    int is64 = *flag;
    for (int k = tid; k < nk; k += 256) {
        long long e = base + k;
        int s = (int)load_idx(ei, is64, e);
        int d = (int)load_idx(ei, is64, E + e);
        int bin = d >> BIN_SHIFT;
        lval[k] = (unsigned)s | ((unsigned)(d & (BIN_SZ - 1)) << 17);
        lbin[k] = (unsigned char)bin;
        atomicAdd(&lcnt[bin], 1);
    }
    __syncthreads();
    for (int i = tid; i < nb; i += 256) {
        int c = lcnt[i];
        lbase[i] = c ? atomicAdd(&cursor[i], c) : 0;
        lcnt[i] = 0;
    }
    __syncthreads();
    for (int k = tid; k < nk; k += 256) {
        int bin = lbin[k];
        int loc = atomicAdd(&lcnt[bin], 1);
        binned[lbase[bin] + loc] = lval[k];
    }
}

// Pass B: one block per bin. From binned records derive per-node degree
// (LDS histogram), rowp, dinv, degree-sorted node permutation, and the
// CSR segment (built in LDS, coalesced copy-out).
__global__ __launch_bounds__(256) void kB(const unsigned* __restrict__ binned,
                                          const int* __restrict__ binStart,
                                          int* __restrict__ rowp, float* __restrict__ dinv,
                                          int* __restrict__ perm, int* __restrict__ cursorG,
                                          int* __restrict__ csr, int N, int E) {
    __shared__ int lcnt[BIN_SZ];
    __shared__ int lexcl[BIN_SZ];
    __shared__ int ls[256];
    __shared__ int dh[64];
    __shared__ int stage[STAGE_CAP];
    int b = blockIdx.x, tid = threadIdx.x;
    int node0 = b << BIN_SHIFT;
    int node1 = min(node0 + BIN_SZ, N);
    int nn = node1 - node0;
    int base = binStart[b];
    int nedges = binStart[b + 1] - base;

    for (int i = tid; i < BIN_SZ; i += 256) lcnt[i] = 0;
    if (tid < 64) dh[tid] = 0;
    __syncthreads();
    for (int t = tid; t < nedges; t += 256)
        atomicAdd(&lcnt[binned[base + t] >> 17], 1);
    __syncthreads();
    // exclusive scan of 512 counts (thread owns elements 2t, 2t+1)
    int c0 = lcnt[2 * tid], c1 = lcnt[2 * tid + 1];
    int loc = c0 + c1;
    ls[tid] = loc;
    __syncthreads();
    for (int off = 1; off < 256; off <<= 1) {
        int t = (tid >= off) ? ls[tid - off] : 0;
        __syncthreads();
        ls[tid] += t;
        __syncthreads();
    }
    int ex = ls[tid] - loc;
    lexcl[2 * tid] = ex;
    lexcl[2 * tid + 1] = ex + c0;
    __syncthreads();
    for (int i = tid; i < nn; i += 256) {
        int deg = lcnt[i];
        rowp[node0 + i] = base + lexcl[i];
        dinv[node0 + i] = rsqrtf(1.0f + (float)deg);
        atomicAdd(&dh[min(deg, 63)], 1);
    }
    if (b == 0 && tid == 0) rowp[N] = E;
    __syncthreads();
    // exclusive scan of 64 degree buckets
    int dv = (tid < 64) ? dh[tid] : 0;
    ls[tid] = dv;
    __syncthreads();
    for (int off = 1; off < 64; off <<= 1) {
        int t = (tid >= off) ? ls[tid - off] : 0;
        __syncthreads();
        ls[tid] += t;
        __syncthreads();
    }
    if (tid < 64) dh[tid] = ls[tid] - dv;
    __syncthreads();
    // degree-sorted permutation (ascending degree within bin)
    for (int i = tid; i < nn; i += 256) {
        int pos = atomicAdd(&dh[min(lcnt[i], 63)], 1);
        perm[node0 + pos] = node0 + i;
    }
    __syncthreads();
    // cursors = lexcl (lcnt reads above are done)
    for (int i = tid; i < BIN_SZ; i += 256) lcnt[i] = lexcl[i];
    __syncthreads();
    if (nedges <= STAGE_CAP) {
        for (int t = tid; t < nedges; t += 256) {
            unsigned v = binned[base + t];
            int src = (int)(v & 0x1FFFFu);
            int dl  = (int)(v >> 17);
            int p = atomicAdd(&lcnt[dl], 1);
            stage[p] = src;
        }
        __syncthreads();
        for (int t = tid; t < nedges; t += 256) csr[base + t] = stage[t];
    } else {
        for (int i = tid; i < nn; i += 256) cursorG[node0 + i] = base + lexcl[i];
        __syncthreads();
        for (int t = tid; t < nedges; t += 256) {
            unsigned v = binned[base + t];
            int src = (int)(v & 0x1FFFFu);
            int dl  = (int)(v >> 17);
            int p = atomicAdd(&cursorG[node0 + dl], 1);
            csr[p] = src;
        }
    }
}

// g[i,c] = fp16( dinv[i] * sum_f x[i,f]*W[c,f] ).
// Block 320 = 32 node-groups x 10 channel-groups; thread: 4 nodes x 4 channels.
__global__ __launch_bounds__(320) void k_gemm(const float* __restrict__ x,
                                              const float* __restrict__ W,
                                              const float* __restrict__ dinv,
                                              unsigned* __restrict__ g, int N) {
    __shared__ float wt[FDIM * WROW];
    int tid = threadIdx.x;
    for (int idx = tid; idx < CDIM * FDIM; idx += 320) {
        int c = idx >> 7, f = idx & 127;
        wt[f * WROW + c] = W[idx];
    }
    __syncthreads();
    int tc = tid % 10;
    int tn = tid / 10;
    int n0 = blockIdx.x * 128 + tn * 4;
    if (n0 >= N) return;
    const float4* xr0 = (const float4*)(x + (size_t)(n0 + 0) * FDIM);
    const float4* xr1 = (const float4*)(x + (size_t)(n0 + 1) * FDIM);
    const float4* xr2 = (const float4*)(x + (size_t)(n0 + 2) * FDIM);
    const float4* xr3 = (const float4*)(x + (size_t)(n0 + 3) * FDIM);
    float4 acc0 = {0,0,0,0}, acc1 = {0,0,0,0}, acc2 = {0,0,0,0}, acc3 = {0,0,0,0};
#pragma unroll 4
    for (int f4 = 0; f4 < FDIM / 4; ++f4) {
        float4 x0 = xr0[f4], x1 = xr1[f4], x2 = xr2[f4], x3 = xr3[f4];
#pragma unroll
        for (int k = 0; k < 4; ++k) {
            int f = 4 * f4 + k;
            float4 wv = *(const float4*)&wt[f * WROW + tc * 4];
            float s0 = k == 0 ? x0.x : k == 1 ? x0.y : k == 2 ? x0.z : x0.w;
            float s1 = k == 0 ? x1.x : k == 1 ? x1.y : k == 2 ? x1.z : x1.w;
            float s2 = k == 0 ? x2.x : k == 1 ? x2.y : k == 2 ? x2.z : x2.w;
            float s3 = k == 0 ? x3.x : k == 1 ? x3.y : k == 2 ? x3.z : x3.w;
            fma4(acc0, s0, wv);
            fma4(acc1, s1, wv);
            fma4(acc2, s2, wv);
            fma4(acc3, s3, wv);
        }
    }
    float d0 = dinv[n0], d1 = dinv[n0 + 1], d2 = dinv[n0 + 2], d3 = dinv[n0 + 3];
    uint2 o0, o1, o2, o3;
    o0.x = packh2(acc0.x * d0, acc0.y * d0); o0.y = packh2(acc0.z * d0, acc0.w * d0);
    o1.x = packh2(acc1.x * d1, acc1.y * d1); o1.y = packh2(acc1.z * d1, acc1.w * d1);
    o2.x = packh2(acc2.x * d2, acc2.y * d2); o2.y = packh2(acc2.z * d2, acc2.w * d2);
    o3.x = packh2(acc3.x * d3, acc3.y * d3); o3.y = packh2(acc3.z * d3, acc3.w * d3);
    ((uint2*)g)[(size_t)(n0 + 0) * 10 + tc] = o0;
    ((uint2*)g)[(size_t)(n0 + 1) * 10 + tc] = o1;
    ((uint2*)g)[(size_t)(n0 + 2) * 10 + tc] = o2;
    ((uint2*)g)[(size_t)(n0 + 3) * 10 + tc] = o3;
}

// One hop in g-space, split 5 ways per node: thread = (node, 8-channel chunk).
// 5N threads; per edge each thread loads one uint4 (16B); 4-edge unroll for MLP.
// mode 0: gout = fp16( dinv^2 * (self + sum) )     [hop 1]
// mode 1: gout = fp32( dinv   * (self + sum) + b ) [hop 2, final output]
__global__ __launch_bounds__(256) void k_gather(const int* __restrict__ rowp,
                                                const int* __restrict__ csr,
                                                const int* __restrict__ perm,
                                                const float* __restrict__ dinv,
                                                const unsigned* __restrict__ gin,
                                                const float* __restrict__ b,
                                                void* __restrict__ gout, int N, int mode) {
    unsigned t = blockIdx.x * 256 + threadIdx.x;
    unsigned gidx = t / 5, c = t - gidx * 5;
    if (gidx >= (unsigned)N) return;
    int node = perm[gidx];
    const uint4* g4 = (const uint4*)gin + c;   // chunk offset; index by 5*row
    float acc[8];
    {
        uint4 sv = g4[(size_t)node * 5];
#pragma unroll
        for (int i = 0; i < 8; ++i) acc[i] = 0.0f;
        addv(acc, sv);
    }
    int j = rowp[node], end = rowp[node + 1];
    for (; j + 3 < end; j += 4) {
        int s0 = csr[j], s1 = csr[j + 1], s2 = csr[j + 2], s3 = csr[j + 3];
        uint4 v0 = g4[(size_t)s0 * 5];
        uint4 v1 = g4[(size_t)s1 * 5];
        uint4 v2 = g4[(size_t)s2 * 5];
        uint4 v3 = g4[(size_t)s3 * 5];
        addv(acc, v0); addv(acc, v1); addv(acc, v2); addv(acc, v3);
    }
    for (; j < end; ++j) {
        uint4 v0 = g4[(size_t)csr[j] * 5];
        addv(acc, v0);
    }
    float d = dinv[node];
    if (mode == 0) {
        float s = d * d;
        uint4 o;
        unsigned* w = (unsigned*)&o;
#pragma unroll
        for (int k = 0; k < 4; ++k)
            w[k] = packh2(acc[2 * k] * s, acc[2 * k + 1] * s);
        ((uint4*)gout)[(size_t)node * 5 + c] = o;
    } else {
        const float4* b4 = (const float4*)b;
        float4 bv0 = b4[2 * c], bv1 = b4[2 * c + 1];
        float4 o0, o1;
        o0.x = acc[0] * d + bv0.x; o0.y = acc[1] * d + bv0.y;
        o0.z = acc[2] * d + bv0.z; o0.w = acc[3] * d + bv0.w;
        o1.x = acc[4] * d + bv1.x; o1.y = acc[5] * d + bv1.y;
        o1.z = acc[6] * d + bv1.z; o1.w = acc[7] * d + bv1.w;
        float4* op = (float4*)gout + (size_t)node * 10 + 2 * c;
        op[0] = o0;
        op[1] = o1;
    }
}

static inline size_t align256(size_t v) { return (v + 255) & ~(size_t)255; }

extern "C" void kernel_launch(void* const* d_in, const int* in_sizes, int n_in,
                              void* d_out, int out_size, void* d_ws, size_t ws_size,
                              hipStream_t stream) {
    const float* x  = (const float*)d_in[0];
    const void*  ei = d_in[1];
    const float* W  = (const float*)d_in[2];
    const float* b  = (const float*)d_in[3];
    float* out = (float*)d_out;

    const int N = in_sizes[0] / FDIM;                 // 100000
    const long long E = (long long)in_sizes[1] / 2;   // 1600000

    const int nb     = (N + BIN_SZ - 1) >> BIN_SHIFT;        // 196 bins
    const int nchunk = (int)((E + CHUNK - 1) / CHUNK);       // 391 chunks

    char* wsb = (char*)d_ws;
    size_t off = 0;
    int*      flag     = (int*)(wsb + off);      off = align256(off + 4);
    int*      btot     = (int*)(wsb + off);      off = align256(off + (size_t)nb * 4);
    int*      binStart = (int*)(wsb + off);      off = align256(off + (size_t)(nb + 1) * 4);
    int*      cursor   = (int*)(wsb + off);      off = align256(off + (size_t)nb * 4);
    int*      rowp     = (int*)(wsb + off);      off = align256(off + (size_t)(N + 1) * 4);
    int*      cursorG  = (int*)(wsb + off);      off = align256(off + (size_t)N * 4);
    int*      perm     = (int*)(wsb + off);      off = align256(off + (size_t)N * 4);
    float*    dinv     = (float*)(wsb + off);    off = align256(off + (size_t)N * 4);
    unsigned* g0       = (unsigned*)(wsb + off); off = align256(off + (size_t)N * CDIM * 2);
    unsigned* g1       = (unsigned*)(wsb + off); off = align256(off + (size_t)N * CDIM * 2);
    unsigned* binned   = (unsigned*)(wsb + off); off = align256(off + (size_t)E * 4);
    int*      csr      = (int*)(wsb + off);      off = align256(off + (size_t)E * 4);

    const int B = 256;
    const int nbGE = (N + 127) / 128;
    const unsigned GT = 5u * (unsigned)N;             // gather threads
    const int nbGA = (int)((GT + B - 1) / B);

    int nscan = (int)((2 * E < 4096) ? (2 * E) : 4096);

    k_detect<<<1, 256, 0, stream>>>((const unsigned int*)ei, nscan, flag, btot, nb);
    kCount  <<<nchunk, B, 0, stream>>>(ei, flag, E, nb, btot);
    kScanB  <<<1, 256, 0, stream>>>(btot, binStart, cursor, nb, (int)E);
    kA3     <<<nchunk, B, 0, stream>>>(ei, flag, E, nb, cursor, binned);
    kB      <<<nb, B, 0, stream>>>(binned, binStart, rowp, dinv, perm, cursorG, csr, N, (int)E);
    k_gemm  <<<nbGE, 320, 0, stream>>>(x, W, dinv, g0, N);
    k_gather<<<nbGA, B, 0, stream>>>(rowp, csr, perm, dinv, g0, b, (void*)g1, N, 0);
    k_gather<<<nbGA, B, 0, stream>>>(rowp, csr, perm, dinv, g1, b, (void*)out, N, 1);
}